// Round 1
// baseline (98.560 us; speedup 1.0000x reference)
//
#include <hip/hip_runtime.h>
#include <math.h>

// Problem constants (from reference): x (8,16,512,64) fp32, flat = [wk|wq] 2*(64*4)
constexpr int kDIn  = 64;
constexpr int kN    = 512;   // rows/cols per (b,t) tile
constexpr int kTopK = 12;
// exp(SCALE*(h-m)) = exp2(CEXP*(h-m)); SCALE = 1/sqrt(64) = 0.125; CEXP = 0.125*log2(e)
#define CEXP 0.18033688f

__global__ __launch_bounds__(512, 1) void sparse_attn_topk(
    const float* __restrict__ x,
    const float* __restrict__ flat,
    int* __restrict__ out)
{
  __shared__ float4 wk4[kDIn];   // wk[c][0..3]
  __shared__ float4 wq4[kDIn];   // wq[c][0..3]
  __shared__ float4 Ks[kN];
  __shared__ float4 Qs[kN];
  __shared__ float  Ms[kN];      // per-row max of raw h
  __shared__ float  Rl[kN];      // per-row 1/sum(exp)
  __shared__ float  As[kN];      // column scores

  const int tid = threadIdx.x;
  const int bt  = blockIdx.x;

  // ---- stage weights: flat is 128 float4s, first 64 = wk rows, next 64 = wq rows
  if (tid < 64)       wk4[tid]      = reinterpret_cast<const float4*>(flat)[tid];
  else if (tid < 128) wq4[tid - 64] = reinterpret_cast<const float4*>(flat)[tid];
  __syncthreads();

  // ---- phase 1: thread i computes K_i, Q_i (kept in registers + stored to LDS)
  const float* xr = x + ((size_t)bt * kN + tid) * kDIn;
  float k0=0.f,k1=0.f,k2=0.f,k3=0.f, q0=0.f,q1=0.f,q2=0.f,q3=0.f;
#pragma unroll
  for (int c = 0; c < kDIn; ++c) {
    float xv = xr[c];
    float4 a = wk4[c];
    float4 b = wq4[c];
    k0 = fmaf(xv, a.x, k0); k1 = fmaf(xv, a.y, k1);
    k2 = fmaf(xv, a.z, k2); k3 = fmaf(xv, a.w, k3);
    q0 = fmaf(xv, b.x, q0); q1 = fmaf(xv, b.y, q1);
    q2 = fmaf(xv, b.z, q2); q3 = fmaf(xv, b.w, q3);
  }
  Ks[tid] = make_float4(k0, k1, k2, k3);
  Qs[tid] = make_float4(q0, q1, q2, q3);
  __syncthreads();

  // ---- phase 2a: row max (pass A) and row denom (pass B); thread i owns row i
  float m = -INFINITY;
#pragma unroll 8
  for (int j = 0; j < kN; ++j) {
    float4 qj = Qs[j];
    float h = fmaf(k0, qj.x, fmaf(k1, qj.y, fmaf(k2, qj.z, k3 * qj.w)));
    m = fmaxf(m, h);
  }
  float l = 0.f;
#pragma unroll 8
  for (int j = 0; j < kN; ++j) {
    float4 qj = Qs[j];
    float h = fmaf(k0, qj.x, fmaf(k1, qj.y, fmaf(k2, qj.z, k3 * qj.w)));
    l += exp2f(CEXP * (h - m));
  }
  Ms[tid] = m;
  Rl[tid] = 1.0f / l;
  __syncthreads();

  // ---- phase 2b: thread j owns column j (its own Q_j is already in q0..q3)
  float acc = 0.f;
#pragma unroll 8
  for (int i = 0; i < kN; ++i) {
    float4 ki = Ks[i];
    float h = fmaf(q0, ki.x, fmaf(q1, ki.y, fmaf(q2, ki.z, q3 * ki.w)));
    acc += exp2f(CEXP * (h - Ms[i])) * Rl[i];
  }
  As[tid] = acc;
  __syncthreads();

  // ---- phase 3: wave 0 extracts top-12 via 12 rounds of 64-lane butterfly argmax
  if (tid < 64) {
    float v[8];
#pragma unroll
    for (int r = 0; r < 8; ++r) v[r] = As[tid * 8 + r];

    for (int rnd = 0; rnd < kTopK; ++rnd) {
      // local argmax over 8 register values; ascending scan + strict '>' keeps lowest index on tie
      float bv = v[0];
      int   bi = tid * 8;
#pragma unroll
      for (int r = 1; r < 8; ++r) {
        if (v[r] > bv) { bv = v[r]; bi = tid * 8 + r; }
      }
      // 64-lane butterfly; lexicographic (value desc, index asc) total order -> all lanes converge
#pragma unroll
      for (int off = 32; off >= 1; off >>= 1) {
        float ov = __shfl_xor(bv, off);
        int   oi = __shfl_xor(bi, off);
        if (ov > bv || (ov == bv && oi < bi)) { bv = ov; bi = oi; }
      }
      if (tid == 0) out[bt * kTopK + rnd] = bi;
      // invalidate the winner (constant-index unrolled so v[] stays in registers)
#pragma unroll
      for (int r = 0; r < 8; ++r) {
        if (tid * 8 + r == bi) v[r] = -INFINITY;
      }
    }
  }
}

extern "C" void kernel_launch(void* const* d_in, const int* in_sizes, int n_in,
                              void* d_out, int out_size, void* d_ws, size_t ws_size,
                              hipStream_t stream) {
  const float* x    = (const float*)d_in[0];
  const float* flat = (const float*)d_in[1];
  int* out = (int*)d_out;
  const int n_bt = in_sizes[0] / (kN * kDIn);   // 8*16 = 128
  sparse_attn_topk<<<n_bt, kN, 0, stream>>>(x, flat, out);
}

// Round 2
// 62.281 us; speedup vs baseline: 1.5825x; 1.5825x over previous
//
#include <hip/hip_runtime.h>
#include <math.h>

// x: (8,16,512,64) fp32; flat = [wk | wq], each (64,4). Output: int32 top-12 idx.
constexpr int kDIn  = 64;
constexpr int kN    = 512;
constexpr int kTopK = 12;
constexpr int kNBt  = 128;          // 8*16
// exp(SCALE*(h-m)) = exp2(CEXP*(h-m)); SCALE = 0.125; CEXP = SCALE*log2(e)
#define CEXP 0.18033688f

// ---- workspace layout (floats) ----
// Kp : [128][512][4]  scaled K' = CEXP*K          262144
// Qp : [128][512][4]                               262144
// M  : [128][512]  row max (CEXP scale)             65536
// R  : [128][512]  1/rowsum                         65536
// P  : [128][4][512] column partial sums           262144
constexpr size_t kOffK = 0;
constexpr size_t kOffQ = kOffK + (size_t)kNBt * kN * 4;
constexpr size_t kOffM = kOffQ + (size_t)kNBt * kN * 4;
constexpr size_t kOffR = kOffM + (size_t)kNBt * kN;
constexpr size_t kOffP = kOffR + (size_t)kNBt * kN;
constexpr size_t kWsFloats = kOffP + (size_t)kNBt * 4 * kN;

// ============ K1: X*Wk, X*Wq projection; grid 512 (bt*4), block 128 ============
__global__ __launch_bounds__(128) void kq_kernel(
    const float* __restrict__ x, const float* __restrict__ flat, float* __restrict__ ws)
{
  __shared__ float4 wk4[kDIn];
  __shared__ float4 wq4[kDIn];
  const int tid = threadIdx.x;
  if (tid < 64) wk4[tid]      = reinterpret_cast<const float4*>(flat)[tid];
  else          wq4[tid - 64] = reinterpret_cast<const float4*>(flat)[tid];
  __syncthreads();

  const int bt  = blockIdx.x >> 2;
  const int row = ((blockIdx.x & 3) << 7) + tid;
  const float4* xr4 = reinterpret_cast<const float4*>(x + ((size_t)bt * kN + row) * kDIn);

  float k0=0.f,k1=0.f,k2=0.f,k3=0.f, q0=0.f,q1=0.f,q2=0.f,q3=0.f;
#pragma unroll
  for (int cc = 0; cc < kDIn / 4; ++cc) {
    float4 xv = xr4[cc];
#pragma unroll
    for (int u = 0; u < 4; ++u) {
      float v = (u==0)?xv.x:(u==1)?xv.y:(u==2)?xv.z:xv.w;
      float4 a = wk4[cc*4+u];
      float4 b = wq4[cc*4+u];
      k0 = fmaf(v, a.x, k0); k1 = fmaf(v, a.y, k1);
      k2 = fmaf(v, a.z, k2); k3 = fmaf(v, a.w, k3);
      q0 = fmaf(v, b.x, q0); q1 = fmaf(v, b.y, q1);
      q2 = fmaf(v, b.z, q2); q3 = fmaf(v, b.w, q3);
    }
  }
  float4* Kp4 = reinterpret_cast<float4*>(ws + kOffK);
  float4* Qp4 = reinterpret_cast<float4*>(ws + kOffQ);
  Kp4[(size_t)bt * kN + row] = make_float4(CEXP*k0, CEXP*k1, CEXP*k2, CEXP*k3);
  Qp4[(size_t)bt * kN + row] = make_float4(q0, q1, q2, q3);
}

// ============ K2: row max + 1/rowsum; grid 512 (bt*4), block 512, 4 thr/row ============
__global__ __launch_bounds__(512) void rowstats_kernel(float* __restrict__ ws)
{
  __shared__ float4 Qs[kN];
  const int tid   = threadIdx.x;
  const int bt    = blockIdx.x >> 2;
  const int chunk = blockIdx.x & 3;

  const float4* Kp4 = reinterpret_cast<const float4*>(ws + kOffK);
  const float4* Qp4 = reinterpret_cast<const float4*>(ws + kOffQ);
  Qs[tid] = Qp4[(size_t)bt * kN + tid];
  __syncthreads();

  const int row = (chunk << 7) + (tid >> 2);
  const int j0  = (tid & 3) << 7;          // 128-wide slice of j
  float4 k = Kp4[(size_t)bt * kN + row];   // already CEXP-scaled

  float m = -INFINITY;
#pragma unroll 8
  for (int j = j0; j < j0 + 128; ++j) {
    float4 qj = Qs[j];
    float h = fmaf(k.x, qj.x, fmaf(k.y, qj.y, fmaf(k.z, qj.z, k.w * qj.w)));
    m = fmaxf(m, h);
  }
  m = fmaxf(m, __shfl_xor(m, 1));
  m = fmaxf(m, __shfl_xor(m, 2));          // group-wide row max

  float l = 0.f;
#pragma unroll 8
  for (int j = j0; j < j0 + 128; ++j) {
    float4 qj = Qs[j];
    float h = fmaf(k.x, qj.x, fmaf(k.y, qj.y, fmaf(k.z, qj.z, k.w * qj.w)));
    l += exp2f(h - m);
  }
  l += __shfl_xor(l, 1);
  l += __shfl_xor(l, 2);

  if ((tid & 3) == 0) {
    ws[kOffM + (size_t)bt * kN + row] = m;
    ws[kOffR + (size_t)bt * kN + row] = 1.0f / l;
  }
}

// ============ K3: column partial sums over 128-row chunk; grid 512, block 512 ============
__global__ __launch_bounds__(512) void colsum_kernel(float* __restrict__ ws)
{
  __shared__ float4 Kc[128];
  __shared__ float  Mc[128];
  __shared__ float  Rc[128];
  const int tid   = threadIdx.x;
  const int bt    = blockIdx.x >> 2;
  const int chunk = blockIdx.x & 3;

  const float4* Kp4 = reinterpret_cast<const float4*>(ws + kOffK);
  const float4* Qp4 = reinterpret_cast<const float4*>(ws + kOffQ);
  if (tid < 128) {
    int i = (chunk << 7) + tid;
    Kc[tid] = Kp4[(size_t)bt * kN + i];
    Mc[tid] = ws[kOffM + (size_t)bt * kN + i];
    Rc[tid] = ws[kOffR + (size_t)bt * kN + i];
  }
  __syncthreads();

  float4 q = Qp4[(size_t)bt * kN + tid];   // thread owns column tid
  float acc = 0.f;
#pragma unroll 8
  for (int i = 0; i < 128; ++i) {
    float4 ki = Kc[i];
    float h = fmaf(q.x, ki.x, fmaf(q.y, ki.y, fmaf(q.z, ki.z, q.w * ki.w)));
    acc += exp2f(h - Mc[i]) * Rc[i];
  }
  ws[kOffP + ((size_t)bt * 4 + chunk) * kN + tid] = acc;
}

// ============ K4: reduce partials + top-12; grid 128, block 64 (one wave) ============
__global__ __launch_bounds__(64) void topk_kernel(const float* __restrict__ ws, int* __restrict__ out)
{
  const int lane = threadIdx.x;
  const int bt   = blockIdx.x;
  const float* P = ws + kOffP + (size_t)bt * 4 * kN;

  float v[8];
#pragma unroll
  for (int r = 0; r < 8; ++r) {
    int j = lane * 8 + r;
    v[r] = P[0*kN + j] + P[1*kN + j] + P[2*kN + j] + P[3*kN + j];
  }

  for (int rnd = 0; rnd < kTopK; ++rnd) {
    float bv = v[0];
    int   bi = lane * 8;
#pragma unroll
    for (int r = 1; r < 8; ++r) {
      if (v[r] > bv) { bv = v[r]; bi = lane * 8 + r; }
    }
#pragma unroll
    for (int off = 32; off >= 1; off >>= 1) {
      float ov = __shfl_xor(bv, off);
      int   oi = __shfl_xor(bi, off);
      if (ov > bv || (ov == bv && oi < bi)) { bv = ov; bi = oi; }
    }
    if (lane == 0) out[bt * kTopK + rnd] = bi;
#pragma unroll
    for (int r = 0; r < 8; ++r) {
      if (lane * 8 + r == bi) v[r] = -INFINITY;
    }
  }
}

// ============ fallback: round-1 single kernel (used only if ws too small) ============
__global__ __launch_bounds__(512, 1) void sparse_attn_topk_fallback(
    const float* __restrict__ x, const float* __restrict__ flat, int* __restrict__ out)
{
  __shared__ float4 wk4[kDIn];
  __shared__ float4 wq4[kDIn];
  __shared__ float4 Ks[kN];
  __shared__ float4 Qs[kN];
  __shared__ float  Ms[kN];
  __shared__ float  Rl[kN];
  __shared__ float  As[kN];

  const int tid = threadIdx.x;
  const int bt  = blockIdx.x;

  if (tid < 64)       wk4[tid]      = reinterpret_cast<const float4*>(flat)[tid];
  else if (tid < 128) wq4[tid - 64] = reinterpret_cast<const float4*>(flat)[tid];
  __syncthreads();

  const float* xr = x + ((size_t)bt * kN + tid) * kDIn;
  float k0=0.f,k1=0.f,k2=0.f,k3=0.f, q0=0.f,q1=0.f,q2=0.f,q3=0.f;
#pragma unroll
  for (int c = 0; c < kDIn; ++c) {
    float xv = xr[c];
    float4 a = wk4[c];
    float4 b = wq4[c];
    k0 = fmaf(xv, a.x, k0); k1 = fmaf(xv, a.y, k1);
    k2 = fmaf(xv, a.z, k2); k3 = fmaf(xv, a.w, k3);
    q0 = fmaf(xv, b.x, q0); q1 = fmaf(xv, b.y, q1);
    q2 = fmaf(xv, b.z, q2); q3 = fmaf(xv, b.w, q3);
  }
  Ks[tid] = make_float4(k0, k1, k2, k3);
  Qs[tid] = make_float4(q0, q1, q2, q3);
  __syncthreads();

  float m = -INFINITY;
#pragma unroll 8
  for (int j = 0; j < kN; ++j) {
    float4 qj = Qs[j];
    float h = fmaf(k0, qj.x, fmaf(k1, qj.y, fmaf(k2, qj.z, k3 * qj.w)));
    m = fmaxf(m, h);
  }
  float l = 0.f;
#pragma unroll 8
  for (int j = 0; j < kN; ++j) {
    float4 qj = Qs[j];
    float h = fmaf(k0, qj.x, fmaf(k1, qj.y, fmaf(k2, qj.z, k3 * qj.w)));
    l += exp2f(CEXP * (h - m));
  }
  Ms[tid] = m;
  Rl[tid] = 1.0f / l;
  __syncthreads();

  float acc = 0.f;
#pragma unroll 8
  for (int i = 0; i < kN; ++i) {
    float4 ki = Ks[i];
    float h = fmaf(q0, ki.x, fmaf(q1, ki.y, fmaf(q2, ki.z, q3 * ki.w)));
    acc += exp2f(CEXP * (h - Ms[i])) * Rl[i];
  }
  As[tid] = acc;
  __syncthreads();

  if (tid < 64) {
    float v[8];
#pragma unroll
    for (int r = 0; r < 8; ++r) v[r] = As[tid * 8 + r];
    for (int rnd = 0; rnd < kTopK; ++rnd) {
      float bv = v[0];
      int   bi = tid * 8;
#pragma unroll
      for (int r = 1; r < 8; ++r)
        if (v[r] > bv) { bv = v[r]; bi = tid * 8 + r; }
#pragma unroll
      for (int off = 32; off >= 1; off >>= 1) {
        float ov = __shfl_xor(bv, off);
        int   oi = __shfl_xor(bi, off);
        if (ov > bv || (ov == bv && oi < bi)) { bv = ov; bi = oi; }
      }
      if (tid == 0) out[bt * kTopK + rnd] = bi;
#pragma unroll
      for (int r = 0; r < 8; ++r)
        if (tid * 8 + r == bi) v[r] = -INFINITY;
    }
  }
}

extern "C" void kernel_launch(void* const* d_in, const int* in_sizes, int n_in,
                              void* d_out, int out_size, void* d_ws, size_t ws_size,
                              hipStream_t stream) {
  const float* x    = (const float*)d_in[0];
  const float* flat = (const float*)d_in[1];
  int* out = (int*)d_out;

  if (ws_size < kWsFloats * sizeof(float)) {
    // not enough scratch — proven single-kernel path
    sparse_attn_topk_fallback<<<kNBt, kN, 0, stream>>>(x, flat, out);
    return;
  }
  float* ws = (float*)d_ws;
  kq_kernel      <<<kNBt * 4, 128, 0, stream>>>(x, flat, ws);
  rowstats_kernel<<<kNBt * 4, 512, 0, stream>>>(ws);
  colsum_kernel  <<<kNBt * 4, 512, 0, stream>>>(ws);
  topk_kernel    <<<kNBt,      64, 0, stream>>>(ws, out);
}

// Round 4
// 46.504 us; speedup vs baseline: 2.1194x; 1.3393x over previous
//
#include <hip/hip_runtime.h>
#include <math.h>

// x: (8,16,512,64) fp32; flat = [wk | wq], each (64,4). Output: int32 top-12 idx.
constexpr int kDIn  = 64;
constexpr int kN    = 512;
constexpr int kTopK = 12;
constexpr int kNBt  = 128;          // 8*16
// exp(SCALE*h) = exp2(CEXP*h); SCALE = 0.125; CEXP = SCALE*log2(e)
#define CEXP 0.18033688f
#define EXP2(v) __builtin_amdgcn_exp2f(v)

// ---- workspace layout (floats) ----
constexpr size_t kOffK  = 0;                                   // Kp [128][512][4] (CEXP-scaled)
constexpr size_t kOffQ  = kOffK  + (size_t)kNBt * kN * 4;      // Qp [128][512][4]
constexpr size_t kOffMp = kOffQ  + (size_t)kNBt * kN * 4;      // mpart [128][2][512]
constexpr size_t kOffLp = kOffMp + (size_t)kNBt * 2 * kN;      // lpart [128][2][512]
constexpr size_t kOffP  = kOffLp + (size_t)kNBt * 2 * kN;      // P [128][4][512]
constexpr size_t kWsFloats = kOffP + (size_t)kNBt * 4 * kN;

// ============ K1: X*Wk, X*Wq projection; grid 512 (bt*4), block 128 ============
__global__ __launch_bounds__(128) void kq_kernel(
    const float* __restrict__ x, const float* __restrict__ flat, float* __restrict__ ws)
{
  __shared__ float4 wk4[kDIn];
  __shared__ float4 wq4[kDIn];
  const int tid = threadIdx.x;
  if (tid < 64) wk4[tid]      = reinterpret_cast<const float4*>(flat)[tid];
  else          wq4[tid - 64] = reinterpret_cast<const float4*>(flat)[tid];
  __syncthreads();

  const int bt  = blockIdx.x >> 2;
  const int row = ((blockIdx.x & 3) << 7) + tid;
  const float4* xr4 = reinterpret_cast<const float4*>(x + ((size_t)bt * kN + row) * kDIn);

  float k0=0.f,k1=0.f,k2=0.f,k3=0.f, q0=0.f,q1=0.f,q2=0.f,q3=0.f;
#pragma unroll
  for (int cc = 0; cc < kDIn / 4; ++cc) {
    float4 xv = xr4[cc];
#pragma unroll
    for (int u = 0; u < 4; ++u) {
      float v = (u==0)?xv.x:(u==1)?xv.y:(u==2)?xv.z:xv.w;
      float4 a = wk4[cc*4+u];
      float4 b = wq4[cc*4+u];
      k0 = fmaf(v, a.x, k0); k1 = fmaf(v, a.y, k1);
      k2 = fmaf(v, a.z, k2); k3 = fmaf(v, a.w, k3);
      q0 = fmaf(v, b.x, q0); q1 = fmaf(v, b.y, q1);
      q2 = fmaf(v, b.z, q2); q3 = fmaf(v, b.w, q3);
    }
  }
  float4* Kp4 = reinterpret_cast<float4*>(ws + kOffK);
  float4* Qp4 = reinterpret_cast<float4*>(ws + kOffQ);
  Kp4[(size_t)bt * kN + row] = make_float4(CEXP*k0, CEXP*k1, CEXP*k2, CEXP*k3);
  Qp4[(size_t)bt * kN + row] = make_float4(q0, q1, q2, q3);
}

// ============ K2: exact row max + exp-sum over a 256-wide j slice ============
// grid 256 (bt*2 + jc), block 512, thread = row. Q_j operand is block-uniform ->
// scalar/broadcast loads straight from global (no LDS).
__global__ __launch_bounds__(512) void rowpart_kernel(
    const float4* __restrict__ kp, const float4* __restrict__ qp,
    float* __restrict__ mpart, float* __restrict__ lpart)
{
  const int tid = threadIdx.x;
  const int bt  = blockIdx.x >> 1;
  const int jc  = blockIdx.x & 1;

  const float4 k = kp[(size_t)bt * kN + tid];            // per-lane, CEXP-scaled
  const float4* qbase = qp + (size_t)bt * kN + jc * 256; // block-uniform

  // pass 1: exact max over 256 j (4 independent max chains)
  float m0 = -INFINITY, m1 = -INFINITY, m2 = -INFINITY, m3 = -INFINITY;
#pragma unroll 4
  for (int j = 0; j < 256; j += 4) {
    float4 qa = qbase[j], qb = qbase[j+1], qc = qbase[j+2], qd = qbase[j+3];
    m0 = fmaxf(m0, fmaf(k.x, qa.x, fmaf(k.y, qa.y, fmaf(k.z, qa.z, k.w * qa.w))));
    m1 = fmaxf(m1, fmaf(k.x, qb.x, fmaf(k.y, qb.y, fmaf(k.z, qb.z, k.w * qb.w))));
    m2 = fmaxf(m2, fmaf(k.x, qc.x, fmaf(k.y, qc.y, fmaf(k.z, qc.z, k.w * qc.w))));
    m3 = fmaxf(m3, fmaf(k.x, qd.x, fmaf(k.y, qd.y, fmaf(k.z, qd.z, k.w * qd.w))));
  }
  const float m = fmaxf(fmaxf(m0, m1), fmaxf(m2, m3));

  // pass 2: sum exp2(h - m) (4 independent add chains)
  float l0 = 0.f, l1 = 0.f, l2 = 0.f, l3 = 0.f;
#pragma unroll 4
  for (int j = 0; j < 256; j += 4) {
    float4 qa = qbase[j], qb = qbase[j+1], qc = qbase[j+2], qd = qbase[j+3];
    l0 += EXP2(fmaf(k.x, qa.x, fmaf(k.y, qa.y, fmaf(k.z, qa.z, k.w * qa.w))) - m);
    l1 += EXP2(fmaf(k.x, qb.x, fmaf(k.y, qb.y, fmaf(k.z, qb.z, k.w * qb.w))) - m);
    l2 += EXP2(fmaf(k.x, qc.x, fmaf(k.y, qc.y, fmaf(k.z, qc.z, k.w * qc.w))) - m);
    l3 += EXP2(fmaf(k.x, qd.x, fmaf(k.y, qd.y, fmaf(k.z, qd.z, k.w * qd.w))) - m);
  }
  mpart[(size_t)blockIdx.x * kN + tid] = m;                     // [bt][jc][row]
  lpart[(size_t)blockIdx.x * kN + tid] = (l0 + l1) + (l2 + l3);
}

// ============ K3: column partials over a 128-row i chunk, merged row stats ============
// grid 512 (bt*4 + ic), block 256, 2 cols/thread. K_i via uniform global loads;
// per-i (max, 1/l) as one float2 LDS broadcast read.
__global__ __launch_bounds__(256) void colsum_kernel(
    const float4* __restrict__ kp, const float4* __restrict__ qp,
    const float* __restrict__ mpart, const float* __restrict__ lpart,
    float* __restrict__ pout)
{
  __shared__ float2 Sc[128];   // {m_i, 1/l_i}
  const int tid = threadIdx.x;
  const int bt  = blockIdx.x >> 2;
  const int ic  = blockIdx.x & 3;

  if (tid < 128) {
    const int i = (ic << 7) + tid;
    const size_t b = (size_t)bt * 2 * kN;
    float ma = mpart[b + i],      mb = mpart[b + kN + i];
    float la = lpart[b + i],      lb = lpart[b + kN + i];
    float m  = fmaxf(ma, mb);
    float l  = fmaf(la, EXP2(ma - m), lb * EXP2(mb - m));
    Sc[tid] = make_float2(m, 1.0f / l);
  }
  __syncthreads();

  const float4 qa = qp[(size_t)bt * kN + tid];         // col tid
  const float4 qb = qp[(size_t)bt * kN + 256 + tid];   // col tid+256
  const float4* kbase = kp + (size_t)bt * kN + (ic << 7);  // block-uniform

  float a0 = 0.f, a1 = 0.f, b0 = 0.f, b1 = 0.f;
#pragma unroll 4
  for (int i = 0; i < 128; i += 2) {
    float4 k0 = kbase[i];
    float4 k1 = kbase[i+1];
    float2 s0 = Sc[i];
    float2 s1 = Sc[i+1];
    a0 = fmaf(EXP2(fmaf(qa.x,k0.x, fmaf(qa.y,k0.y, fmaf(qa.z,k0.z, qa.w*k0.w))) - s0.x), s0.y, a0);
    b0 = fmaf(EXP2(fmaf(qb.x,k0.x, fmaf(qb.y,k0.y, fmaf(qb.z,k0.z, qb.w*k0.w))) - s0.x), s0.y, b0);
    a1 = fmaf(EXP2(fmaf(qa.x,k1.x, fmaf(qa.y,k1.y, fmaf(qa.z,k1.z, qa.w*k1.w))) - s1.x), s1.y, a1);
    b1 = fmaf(EXP2(fmaf(qb.x,k1.x, fmaf(qb.y,k1.y, fmaf(qb.z,k1.z, qb.w*k1.w))) - s1.x), s1.y, b1);
  }
  pout[((size_t)bt * 4 + ic) * kN + tid]       = a0 + a1;
  pout[((size_t)bt * 4 + ic) * kN + 256 + tid] = b0 + b1;
}

// ============ K4: reduce partials + top-12; grid 128, block 64 (one wave) ============
__global__ __launch_bounds__(64) void topk_kernel(const float* __restrict__ ws, int* __restrict__ out)
{
  const int lane = threadIdx.x;
  const int bt   = blockIdx.x;
  const float* P = ws + kOffP + (size_t)bt * 4 * kN;

  float v[8];
#pragma unroll
  for (int r = 0; r < 8; ++r) {
    int j = lane * 8 + r;
    v[r] = (P[0*kN + j] + P[1*kN + j]) + (P[2*kN + j] + P[3*kN + j]);
  }

  for (int rnd = 0; rnd < kTopK; ++rnd) {
    float bv = v[0];
    int   bi = lane * 8;
#pragma unroll
    for (int r = 1; r < 8; ++r) {
      if (v[r] > bv) { bv = v[r]; bi = lane * 8 + r; }
    }
#pragma unroll
    for (int off = 32; off >= 1; off >>= 1) {
      float ov = __shfl_xor(bv, off);
      int   oi = __shfl_xor(bi, off);
      if (ov > bv || (ov == bv && oi < bi)) { bv = ov; bi = oi; }
    }
    if (lane == 0) out[bt * kTopK + rnd] = bi;
#pragma unroll
    for (int r = 0; r < 8; ++r) {
      if (lane * 8 + r == bi) v[r] = -INFINITY;
    }
  }
}

// ============ fallback: round-1 single kernel (used only if ws too small) ============
__global__ __launch_bounds__(512, 1) void sparse_attn_topk_fallback(
    const float* __restrict__ x, const float* __restrict__ flat, int* __restrict__ out)
{
  __shared__ float4 wk4[kDIn];
  __shared__ float4 wq4[kDIn];
  __shared__ float4 Ks[kN];
  __shared__ float4 Qs[kN];
  __shared__ float  Ms[kN];
  __shared__ float  Rl[kN];
  __shared__ float  As[kN];

  const int tid = threadIdx.x;
  const int bt  = blockIdx.x;

  if (tid < 64)       wk4[tid]      = reinterpret_cast<const float4*>(flat)[tid];
  else if (tid < 128) wq4[tid - 64] = reinterpret_cast<const float4*>(flat)[tid];
  __syncthreads();

  const float* xr = x + ((size_t)bt * kN + tid) * kDIn;
  float k0=0.f,k1=0.f,k2=0.f,k3=0.f, q0=0.f,q1=0.f,q2=0.f,q3=0.f;
#pragma unroll
  for (int c = 0; c < kDIn; ++c) {
    float xv = xr[c];
    float4 a = wk4[c];
    float4 b = wq4[c];
    k0 = fmaf(xv, a.x, k0); k1 = fmaf(xv, a.y, k1);
    k2 = fmaf(xv, a.z, k2); k3 = fmaf(xv, a.w, k3);
    q0 = fmaf(xv, b.x, q0); q1 = fmaf(xv, b.y, q1);
    q2 = fmaf(xv, b.z, q2); q3 = fmaf(xv, b.w, q3);
  }
  Ks[tid] = make_float4(k0, k1, k2, k3);
  Qs[tid] = make_float4(q0, q1, q2, q3);
  __syncthreads();

  float m = -INFINITY;
#pragma unroll 8
  for (int j = 0; j < kN; ++j) {
    float4 qj = Qs[j];
    float h = fmaf(k0, qj.x, fmaf(k1, qj.y, fmaf(k2, qj.z, k3 * qj.w)));
    m = fmaxf(m, h);
  }
  float l = 0.f;
#pragma unroll 8
  for (int j = 0; j < kN; ++j) {
    float4 qj = Qs[j];
    float h = fmaf(k0, qj.x, fmaf(k1, qj.y, fmaf(k2, qj.z, k3 * qj.w)));
    l += exp2f(CEXP * (h - m));
  }
  Ms[tid] = m;
  Rl[tid] = 1.0f / l;
  __syncthreads();

  float acc = 0.f;
#pragma unroll 8
  for (int i = 0; i < kN; ++i) {
    float4 ki = Ks[i];
    float h = fmaf(q0, ki.x, fmaf(q1, ki.y, fmaf(q2, ki.z, q3 * ki.w)));
    acc += exp2f(CEXP * (h - Ms[i])) * Rl[i];
  }
  As[tid] = acc;
  __syncthreads();

  if (tid < 64) {
    float v[8];
#pragma unroll
    for (int r = 0; r < 8; ++r) v[r] = As[tid * 8 + r];
    for (int rnd = 0; rnd < kTopK; ++rnd) {
      float bv = v[0];
      int   bi = tid * 8;
#pragma unroll
      for (int r = 1; r < 8; ++r)
        if (v[r] > bv) { bv = v[r]; bi = tid * 8 + r; }
#pragma unroll
      for (int off = 32; off >= 1; off >>= 1) {
        float ov = __shfl_xor(bv, off);
        int   oi = __shfl_xor(bi, off);
        if (ov > bv || (ov == bv && oi < bi)) { bv = ov; bi = oi; }
      }
      if (tid == 0) out[bt * kTopK + rnd] = bi;
#pragma unroll
      for (int r = 0; r < 8; ++r)
        if (tid * 8 + r == bi) v[r] = -INFINITY;
    }
  }
}

extern "C" void kernel_launch(void* const* d_in, const int* in_sizes, int n_in,
                              void* d_out, int out_size, void* d_ws, size_t ws_size,
                              hipStream_t stream) {
  const float* x    = (const float*)d_in[0];
  const float* flat = (const float*)d_in[1];
  int* out = (int*)d_out;

  if (ws_size < kWsFloats * sizeof(float)) {
    sparse_attn_topk_fallback<<<kNBt, kN, 0, stream>>>(x, flat, out);
    return;
  }
  float* ws = (float*)d_ws;
  const float4* kp = reinterpret_cast<const float4*>(ws + kOffK);
  const float4* qp = reinterpret_cast<const float4*>(ws + kOffQ);

  kq_kernel     <<<kNBt * 4, 128, 0, stream>>>(x, flat, ws);
  rowpart_kernel<<<kNBt * 2, 512, 0, stream>>>(kp, qp, ws + kOffMp, ws + kOffLp);
  colsum_kernel <<<kNBt * 4, 256, 0, stream>>>(kp, qp, ws + kOffMp, ws + kOffLp, ws + kOffP);
  topk_kernel   <<<kNBt,      64, 0, stream>>>(ws, out);
}

// Round 6
// 41.937 us; speedup vs baseline: 2.3502x; 1.1089x over previous
//
#include <hip/hip_runtime.h>
#include <math.h>

// x: (8,16,512,64) fp32; flat = [wk | wq], each (64,4). Output: int32 top-12 idx.
constexpr int kDIn  = 64;
constexpr int kN    = 512;
constexpr int kTopK = 12;
constexpr int kNBt  = 128;          // 8*16
// exp(SCALE*h) = exp2(CEXP*h); SCALE = 0.125; CEXP = SCALE*log2(e)
#define CEXP 0.18033688f
#define EXP2(v) __builtin_amdgcn_exp2f(v)
// NUMERIC INVARIANT (R3/R5 post-mortems): every exp2 argument must be <= 0,
// via an EXACT row max. Then terms in [0,1], l in [1,512], r in [2^-9,1] --
// no denormal, no inf, immune to FTZ. Approximate shifts (CS bound, fixed
// -128) both produced inf/NaN tiles.

// ---- workspace layout (floats) ----
constexpr size_t kOffK  = 0;                                   // Kp [128][512][4] (CEXP-scaled)
constexpr size_t kOffQ  = kOffK  + (size_t)kNBt * kN * 4;      // Qp [128][512][4]
constexpr size_t kOffMp = kOffQ  + (size_t)kNBt * kN * 4;      // mpart [128][4][512]
constexpr size_t kOffLp = kOffMp + (size_t)kNBt * 4 * kN;      // lpart [128][4][512]
constexpr size_t kOffP  = kOffLp + (size_t)kNBt * 4 * kN;      // P     [128][4][512]
constexpr size_t kWsFloats = kOffP + (size_t)kNBt * 4 * kN;

// ============ K1: X*Wk, X*Wq projection; grid 512 (bt*4), block 128 ============
__global__ __launch_bounds__(128) void kq_kernel(
    const float* __restrict__ x, const float* __restrict__ flat, float* __restrict__ ws)
{
  __shared__ float4 wk4[kDIn];
  __shared__ float4 wq4[kDIn];
  const int tid = threadIdx.x;
  if (tid < 64) wk4[tid]      = reinterpret_cast<const float4*>(flat)[tid];
  else          wq4[tid - 64] = reinterpret_cast<const float4*>(flat)[tid];
  __syncthreads();

  const int bt  = blockIdx.x >> 2;
  const int row = ((blockIdx.x & 3) << 7) + tid;
  const float4* xr4 = reinterpret_cast<const float4*>(x + ((size_t)bt * kN + row) * kDIn);

  float k0=0.f,k1=0.f,k2=0.f,k3=0.f, q0=0.f,q1=0.f,q2=0.f,q3=0.f;
#pragma unroll
  for (int cc = 0; cc < kDIn / 4; ++cc) {
    float4 xv = xr4[cc];
#pragma unroll
    for (int u = 0; u < 4; ++u) {
      float v = (u==0)?xv.x:(u==1)?xv.y:(u==2)?xv.z:xv.w;
      float4 a = wk4[cc*4+u];
      float4 b = wq4[cc*4+u];
      k0 = fmaf(v, a.x, k0); k1 = fmaf(v, a.y, k1);
      k2 = fmaf(v, a.z, k2); k3 = fmaf(v, a.w, k3);
      q0 = fmaf(v, b.x, q0); q1 = fmaf(v, b.y, q1);
      q2 = fmaf(v, b.z, q2); q3 = fmaf(v, b.w, q3);
    }
  }
  float4* Kp4 = reinterpret_cast<float4*>(ws + kOffK);
  float4* Qp4 = reinterpret_cast<float4*>(ws + kOffQ);
  Kp4[(size_t)bt * kN + row] = make_float4(CEXP*k0, CEXP*k1, CEXP*k2, CEXP*k3);
  Qp4[(size_t)bt * kN + row] = make_float4(q0, q1, q2, q3);
}

// ============ K2: exact per-slice row max + exp-sum over a 128-wide j slice ============
// grid 512 (bt*4 + jq), block 256, 2 rows/thread. Q slice in LDS, wave-uniform
// broadcast reads (conflict-free). Two passes; -m folded into innermost fma.
__global__ __launch_bounds__(256) void rowpart_kernel(
    const float4* __restrict__ kp, const float4* __restrict__ qp,
    float* __restrict__ mpart, float* __restrict__ lpart)
{
  __shared__ float4 Qs[128];
  const int tid = threadIdx.x;
  const int bt  = blockIdx.x >> 2;
  const int jq  = blockIdx.x & 3;

  if (tid < 128) Qs[tid] = qp[(size_t)bt * kN + (jq << 7) + tid];
  __syncthreads();

  const float4 ka = kp[(size_t)bt * kN + tid];          // row tid
  const float4 kb = kp[(size_t)bt * kN + 256 + tid];    // row tid+256

  // pass 1: exact max over the 128-j slice
  float ma0=-INFINITY, ma1=-INFINITY, mb0=-INFINITY, mb1=-INFINITY;
#pragma unroll 4
  for (int j = 0; j < 128; j += 2) {
    float4 q0 = Qs[j], q1 = Qs[j+1];
    ma0 = fmaxf(ma0, fmaf(ka.x,q0.x, fmaf(ka.y,q0.y, fmaf(ka.z,q0.z, ka.w*q0.w))));
    mb0 = fmaxf(mb0, fmaf(kb.x,q0.x, fmaf(kb.y,q0.y, fmaf(kb.z,q0.z, kb.w*q0.w))));
    ma1 = fmaxf(ma1, fmaf(ka.x,q1.x, fmaf(ka.y,q1.y, fmaf(ka.z,q1.z, ka.w*q1.w))));
    mb1 = fmaxf(mb1, fmaf(kb.x,q1.x, fmaf(kb.y,q1.y, fmaf(kb.z,q1.z, kb.w*q1.w))));
  }
  const float ma = fmaxf(ma0, ma1);
  const float mb = fmaxf(mb0, mb1);

  // pass 2: sum exp2(h - m); args <= 0 by construction
  float la0=0.f, la1=0.f, lb0=0.f, lb1=0.f;
#pragma unroll 4
  for (int j = 0; j < 128; j += 2) {
    float4 q0 = Qs[j], q1 = Qs[j+1];
    la0 += EXP2(fmaf(ka.x,q0.x, fmaf(ka.y,q0.y, fmaf(ka.z,q0.z, fmaf(ka.w,q0.w, -ma)))));
    lb0 += EXP2(fmaf(kb.x,q0.x, fmaf(kb.y,q0.y, fmaf(kb.z,q0.z, fmaf(kb.w,q0.w, -mb)))));
    la1 += EXP2(fmaf(ka.x,q1.x, fmaf(ka.y,q1.y, fmaf(ka.z,q1.z, fmaf(ka.w,q1.w, -ma)))));
    lb1 += EXP2(fmaf(kb.x,q1.x, fmaf(kb.y,q1.y, fmaf(kb.z,q1.z, fmaf(kb.w,q1.w, -mb)))));
  }
  mpart[(size_t)blockIdx.x * kN + tid]       = ma;      // [bt][jq][row]
  mpart[(size_t)blockIdx.x * kN + 256 + tid] = mb;
  lpart[(size_t)blockIdx.x * kN + tid]       = la0 + la1;
  lpart[(size_t)blockIdx.x * kN + 256 + tid] = lb0 + lb1;
}

// ============ K3: column partials over a 128-row i chunk ============
// grid 512 (bt*4 + ic), block 256, 2 cols/thread. Merge 4 slice partials into
// (m_i, 1/l_i) exactly as R4 (exp2-scaled, args <= 0). K chunk + stats in LDS.
__global__ __launch_bounds__(256) void colsum_kernel(
    const float4* __restrict__ kp, const float4* __restrict__ qp,
    const float* __restrict__ mpart, const float* __restrict__ lpart,
    float* __restrict__ pout)
{
  __shared__ float4 Kc[128];
  __shared__ float2 Sc[128];   // {m_i, 1/l_i}
  const int tid = threadIdx.x;
  const int bt  = blockIdx.x >> 2;
  const int ic  = blockIdx.x & 3;

  if (tid < 128) {
    const int i = (ic << 7) + tid;
    Kc[tid] = kp[(size_t)bt * kN + i];
    const size_t b = (size_t)bt * 4 * kN;
    float m0 = mpart[b + i],        m1 = mpart[b + kN + i];
    float m2 = mpart[b + 2*kN + i], m3 = mpart[b + 3*kN + i];
    float l0 = lpart[b + i],        l1 = lpart[b + kN + i];
    float l2 = lpart[b + 2*kN + i], l3 = lpart[b + 3*kN + i];
    float m = fmaxf(fmaxf(m0, m1), fmaxf(m2, m3));
    float l = fmaf(l0, EXP2(m0 - m), l1 * EXP2(m1 - m)) +
              fmaf(l2, EXP2(m2 - m), l3 * EXP2(m3 - m));
    Sc[tid] = make_float2(m, 1.0f / l);
  }
  __syncthreads();

  const float4 qa = qp[(size_t)bt * kN + tid];         // col tid
  const float4 qb = qp[(size_t)bt * kN + 256 + tid];   // col tid+256

  float a0 = 0.f, a1 = 0.f, b0 = 0.f, b1 = 0.f;
#pragma unroll 4
  for (int i = 0; i < 128; i += 2) {
    float4 k0 = Kc[i];
    float4 k1 = Kc[i+1];
    float2 s0 = Sc[i];
    float2 s1 = Sc[i+1];
    a0 = fmaf(EXP2(fmaf(qa.x,k0.x, fmaf(qa.y,k0.y, fmaf(qa.z,k0.z, fmaf(qa.w,k0.w, -s0.x))))), s0.y, a0);
    b0 = fmaf(EXP2(fmaf(qb.x,k0.x, fmaf(qb.y,k0.y, fmaf(qb.z,k0.z, fmaf(qb.w,k0.w, -s0.x))))), s0.y, b0);
    a1 = fmaf(EXP2(fmaf(qa.x,k1.x, fmaf(qa.y,k1.y, fmaf(qa.z,k1.z, fmaf(qa.w,k1.w, -s1.x))))), s1.y, a1);
    b1 = fmaf(EXP2(fmaf(qb.x,k1.x, fmaf(qb.y,k1.y, fmaf(qb.z,k1.z, fmaf(qb.w,k1.w, -s1.x))))), s1.y, b1);
  }
  pout[((size_t)bt * 4 + ic) * kN + tid]       = a0 + a1;
  pout[((size_t)bt * 4 + ic) * kN + 256 + tid] = b0 + b1;
}

// ============ K4: reduce partials + top-12; grid 128, block 64 (one wave) ============
__global__ __launch_bounds__(64) void topk_kernel(const float* __restrict__ ws, int* __restrict__ out)
{
  const int lane = threadIdx.x;
  const int bt   = blockIdx.x;
  const float* P = ws + kOffP + (size_t)bt * 4 * kN;

  float v[8];
#pragma unroll
  for (int r = 0; r < 8; ++r) {
    int j = lane * 8 + r;
    v[r] = (P[0*kN + j] + P[1*kN + j]) + (P[2*kN + j] + P[3*kN + j]);
  }

  for (int rnd = 0; rnd < kTopK; ++rnd) {
    float bv = v[0];
    int   bi = lane * 8;
#pragma unroll
    for (int r = 1; r < 8; ++r) {
      if (v[r] > bv) { bv = v[r]; bi = lane * 8 + r; }
    }
#pragma unroll
    for (int off = 32; off >= 1; off >>= 1) {
      float ov = __shfl_xor(bv, off);
      int   oi = __shfl_xor(bi, off);
      if (ov > bv || (ov == bv && oi < bi)) { bv = ov; bi = oi; }
    }
    if (lane == 0) out[bt * kTopK + rnd] = bi;
#pragma unroll
    for (int r = 0; r < 8; ++r) {
      if (lane * 8 + r == bi) v[r] = -INFINITY;
    }
  }
}

// ============ fallback: round-1 single kernel (used only if ws too small) ============
__global__ __launch_bounds__(512, 1) void sparse_attn_topk_fallback(
    const float* __restrict__ x, const float* __restrict__ flat, int* __restrict__ out)
{
  __shared__ float4 wk4[kDIn];
  __shared__ float4 wq4[kDIn];
  __shared__ float4 Ks[kN];
  __shared__ float4 Qs[kN];
  __shared__ float  Ms[kN];
  __shared__ float  Rl[kN];
  __shared__ float  As[kN];

  const int tid = threadIdx.x;
  const int bt  = blockIdx.x;

  if (tid < 64)       wk4[tid]      = reinterpret_cast<const float4*>(flat)[tid];
  else if (tid < 128) wq4[tid - 64] = reinterpret_cast<const float4*>(flat)[tid];
  __syncthreads();

  const float* xr = x + ((size_t)bt * kN + tid) * kDIn;
  float k0=0.f,k1=0.f,k2=0.f,k3=0.f, q0=0.f,q1=0.f,q2=0.f,q3=0.f;
#pragma unroll
  for (int c = 0; c < kDIn; ++c) {
    float xv = xr[c];
    float4 a = wk4[c];
    float4 b = wq4[c];
    k0 = fmaf(xv, a.x, k0); k1 = fmaf(xv, a.y, k1);
    k2 = fmaf(xv, a.z, k2); k3 = fmaf(xv, a.w, k3);
    q0 = fmaf(xv, b.x, q0); q1 = fmaf(xv, b.y, q1);
    q2 = fmaf(xv, b.z, q2); q3 = fmaf(xv, b.w, q3);
  }
  Ks[tid] = make_float4(k0, k1, k2, k3);
  Qs[tid] = make_float4(q0, q1, q2, q3);
  __syncthreads();

  float m = -INFINITY;
#pragma unroll 8
  for (int j = 0; j < kN; ++j) {
    float4 qj = Qs[j];
    float h = fmaf(k0, qj.x, fmaf(k1, qj.y, fmaf(k2, qj.z, k3 * qj.w)));
    m = fmaxf(m, h);
  }
  float l = 0.f;
#pragma unroll 8
  for (int j = 0; j < kN; ++j) {
    float4 qj = Qs[j];
    float h = fmaf(k0, qj.x, fmaf(k1, qj.y, fmaf(k2, qj.z, k3 * qj.w)));
    l += exp2f(CEXP * (h - m));
  }
  Ms[tid] = m;
  Rl[tid] = 1.0f / l;
  __syncthreads();

  float acc = 0.f;
#pragma unroll 8
  for (int i = 0; i < kN; ++i) {
    float4 ki = Ks[i];
    float h = fmaf(q0, ki.x, fmaf(q1, ki.y, fmaf(q2, ki.z, q3 * ki.w)));
    acc += exp2f(CEXP * (h - Ms[i])) * Rl[i];
  }
  As[tid] = acc;
  __syncthreads();

  if (tid < 64) {
    float v[8];
#pragma unroll
    for (int r = 0; r < 8; ++r) v[r] = As[tid * 8 + r];
    for (int rnd = 0; rnd < kTopK; ++rnd) {
      float bv = v[0];
      int   bi = tid * 8;
#pragma unroll
      for (int r = 1; r < 8; ++r)
        if (v[r] > bv) { bv = v[r]; bi = tid * 8 + r; }
#pragma unroll
      for (int off = 32; off >= 1; off >>= 1) {
        float ov = __shfl_xor(bv, off);
        int   oi = __shfl_xor(bi, off);
        if (ov > bv || (ov == bv && oi < bi)) { bv = ov; bi = oi; }
      }
      if (tid == 0) out[bt * kTopK + rnd] = bi;
#pragma unroll
      for (int r = 0; r < 8; ++r)
        if (tid * 8 + r == bi) v[r] = -INFINITY;
    }
  }
}

extern "C" void kernel_launch(void* const* d_in, const int* in_sizes, int n_in,
                              void* d_out, int out_size, void* d_ws, size_t ws_size,
                              hipStream_t stream) {
  const float* x    = (const float*)d_in[0];
  const float* flat = (const float*)d_in[1];
  int* out = (int*)d_out;

  if (ws_size < kWsFloats * sizeof(float)) {
    sparse_attn_topk_fallback<<<kNBt, kN, 0, stream>>>(x, flat, out);
    return;
  }
  float* ws = (float*)d_ws;
  const float4* kp = reinterpret_cast<const float4*>(ws + kOffK);
  const float4* qp = reinterpret_cast<const float4*>(ws + kOffQ);

  kq_kernel     <<<kNBt * 4, 128, 0, stream>>>(x, flat, ws);
  rowpart_kernel<<<kNBt * 4, 256, 0, stream>>>(kp, qp, ws + kOffMp, ws + kOffLp);
  colsum_kernel <<<kNBt * 4, 256, 0, stream>>>(kp, qp, ws + kOffMp, ws + kOffLp, ws + kOffP);
  topk_kernel   <<<kNBt,      64, 0, stream>>>(ws, out);
}